// Round 1
// baseline (243.149 us; speedup 1.0000x reference)
//
#include <hip/hip_runtime.h>
#include <math.h>

// PixPro fused masked all-pairs cosine loss, MI355X (gfx950).
// B=2048, C=256, H=W=7 -> P=49 pixels.
// out[b] = -(1/2401) * sum_{p,q} wt[p][q] * dot(base_p, mom_q)/max(nb_p*nm_q, eps)
// where wt[p][q] = [base_A[p,q]==1] + [moment_A[q,p]==1]   (loss-term fusion).

constexpr int NB     = 2048;
constexpr int NC     = 256;
constexpr int NP     = 49;          // 7*7 pixels
constexpr int SLAB_C = 16;          // channels per slab
constexpr int SLAB_F = SLAB_C * NP; // 784 floats per feature per slab
constexpr int NSLAB  = NC / SLAB_C; // 16
constexpr float EPS  = 1e-6f;

__global__ __launch_bounds__(256, 2)
void pixpro_kernel(const float* __restrict__ gbase,
                   const float* __restrict__ gmom,
                   const int*   __restrict__ A1,
                   const int*   __restrict__ A2,
                   float*       __restrict__ out)
{
    __shared__ float wt[NP * NP];                        // 2401 combined weights
    __shared__ __align__(16) float slab[4][2 * SLAB_F];  // per-wave staging (base|mom)

    const int tid  = threadIdx.x;
    const int wave = tid >> 6;
    const int lane = tid & 63;
    const int b    = blockIdx.x * 4 + wave;

    // --- stage combined mask weights (block-shared, read-only after barrier) ---
    for (int t = tid; t < NP * NP; t += 256) {
        int p = t / NP, q = t - p * NP;
        wt[t] = (A1[t] == 1 ? 1.0f : 0.0f) + (A2[q * NP + p] == 1 ? 1.0f : 0.0f);
    }
    __syncthreads();

    float* sl = slab[wave];

    // lane (lp,lq) owns 7x7 pair tile: p = p0..p0+6, q = q0..q0+6.
    // lp==7 / lq==7 lanes duplicate tile 6 (clamped) and are masked in epilogue.
    const int lp = lane & 7, lq = lane >> 3;
    const int p0 = (lp < 7 ? lp : 6) * 7;
    const int q0 = (lq < 7 ? lq : 6) * 7;

    const float* gb = gbase + (size_t)b * (NC * NP);
    const float* gm = gmom  + (size_t)b * (NC * NP);

    // norm-accumulation assignment: lane l accumulates squared sums for
    //   v0: l<49 -> base pixel l ; l>=49 -> mom pixel l-49     (lds delta below)
    //   v1: l<34 -> mom pixel 15+l (clamped otherwise, result unused)
    const float* vA = sl + ((lane < NP) ? lane : (SLAB_F - NP + lane));
    const float* vB = sl + (SLAB_F + 15 + (lane < 34 ? lane : 33));
    const float* bp = sl + p0;
    const float* mp = sl + SLAB_F + q0;

    float acc[7][7];
    #pragma unroll
    for (int j = 0; j < 7; ++j)
        #pragma unroll
        for (int i = 0; i < 7; ++i) acc[j][i] = 0.0f;
    float nrm0 = 0.0f, nrm1 = 0.0f;

    // --- prefetch slab 0 into registers (196 float4 per feature) ---
    float4 rb0 = {}, rb1 = {}, rb2 = {}, rb3 = {};
    float4 rm0 = {}, rm1 = {}, rm2 = {}, rm3 = {};
    {
        const float4* pb = (const float4*)gb;
        const float4* pm = (const float4*)gm;
        rb0 = pb[lane]; rb1 = pb[lane + 64]; rb2 = pb[lane + 128];
        rm0 = pm[lane]; rm1 = pm[lane + 64]; rm2 = pm[lane + 128];
        if (lane < 4) { rb3 = pb[lane + 192]; rm3 = pm[lane + 192]; }
    }

    for (int s = 0; s < NSLAB; ++s) {
        // write current slab to wave-private LDS
        {
            float4* lb = (float4*)sl;
            float4* lm = (float4*)(sl + SLAB_F);
            lb[lane] = rb0; lb[lane + 64] = rb1; lb[lane + 128] = rb2;
            lm[lane] = rm0; lm[lane + 64] = rm1; lm[lane + 128] = rm2;
            if (lane < 4) { lb[lane + 192] = rb3; lm[lane + 192] = rm3; }
        }
        // prefetch next slab (async; hidden behind compute below)
        if (s + 1 < NSLAB) {
            const float4* pb = (const float4*)(gb + (s + 1) * SLAB_F);
            const float4* pm = (const float4*)(gm + (s + 1) * SLAB_F);
            rb0 = pb[lane]; rb1 = pb[lane + 64]; rb2 = pb[lane + 128];
            rm0 = pm[lane]; rm1 = pm[lane + 64]; rm2 = pm[lane + 128];
            if (lane < 4) { rb3 = pb[lane + 192]; rm3 = pm[lane + 192]; }
        }
        __syncthreads();  // write->read visibility (cheap; uniform trip count)

        // compute: 16 channels x (49 pair FMAs + 2 norm FMAs + 16 lds reads)
        #pragma unroll
        for (int c = 0; c < SLAB_C; ++c) {
            float bv[7], mv[7];
            #pragma unroll
            for (int i = 0; i < 7; ++i) bv[i] = bp[c * NP + i];
            #pragma unroll
            for (int j = 0; j < 7; ++j) mv[j] = mp[c * NP + j];
            float v0 = vA[c * NP];
            float v1 = vB[c * NP];
            nrm0 = fmaf(v0, v0, nrm0);
            nrm1 = fmaf(v1, v1, nrm1);
            #pragma unroll
            for (int j = 0; j < 7; ++j)
                #pragma unroll
                for (int i = 0; i < 7; ++i)
                    acc[j][i] = fmaf(bv[i], mv[j], acc[j][i]);
        }
        __syncthreads();  // reads done before next iteration's writes (paranoia)
    }

    // --- exchange squared norms through (now free) slab space ---
    // layout: nsq[0..48] = sum base^2 per p ; nsq[49..97] = sum mom^2 per q
    float* nsq = sl;
    nsq[lane] = nrm0;                         // lanes 0..48 -> sb[p]; 49..63 -> sm[0..14]
    if (lane < 34) nsq[64 + lane] = nrm1;     // sm[15..48]
    __syncthreads();

    float nbv[7], nmv[7];
    #pragma unroll
    for (int i = 0; i < 7; ++i) nbv[i] = sqrtf(nsq[p0 + i]);
    #pragma unroll
    for (int j = 0; j < 7; ++j) nmv[j] = sqrtf(nsq[NP + q0 + j]);

    float sum = 0.0f;
    if (lp < 7 && lq < 7) {
        #pragma unroll
        for (int j = 0; j < 7; ++j) {
            #pragma unroll
            for (int i = 0; i < 7; ++i) {
                float w     = wt[(p0 + i) * NP + (q0 + j)];
                float denom = fmaxf(nbv[i] * nmv[j], EPS);
                sum += w * acc[j][i] / denom;
            }
        }
    }

    // 64-lane butterfly reduction
    #pragma unroll
    for (int m = 32; m; m >>= 1) sum += __shfl_xor(sum, m, 64);

    if (lane == 0) out[b] = sum * (-1.0f / 2401.0f);
}

extern "C" void kernel_launch(void* const* d_in, const int* in_sizes, int n_in,
                              void* d_out, int out_size, void* d_ws, size_t ws_size,
                              hipStream_t stream)
{
    (void)in_sizes; (void)n_in; (void)d_ws; (void)ws_size; (void)out_size;
    const float* base = (const float*)d_in[0];
    const float* mom  = (const float*)d_in[1];
    const int*   A1   = (const int*)d_in[2];
    const int*   A2   = (const int*)d_in[3];
    float*       out  = (float*)d_out;

    pixpro_kernel<<<NB / 4, 256, 0, stream>>>(base, mom, A1, A2, out);
}